// Round 1
// baseline (278.415 us; speedup 1.0000x reference)
//
#include <hip/hip_runtime.h>
#include <hip/hip_bf16.h>
#include <stdint.h>

// Problem dims (fixed): B=4, S=2048, IN=1024, OUT=4096 -> M=8192, K=1024, N=4096
#define M_DIM 8192
#define K_DIM 1024
#define N_DIM 4096

typedef __bf16 bf16x8 __attribute__((ext_vector_type(8)));
typedef float  f32x4  __attribute__((ext_vector_type(4)));

__device__ __forceinline__ uint16_t f2bf(float f) {
  union { float f; uint32_t u; } x; x.f = f;
  uint32_t u = x.u;
  return (uint16_t)((u + 0x7FFFu + ((u >> 16) & 1u)) >> 16);  // RNE
}

// ---------------- kernel 1: input fp32 -> bf16 ----------------
__global__ __launch_bounds__(256) void convert_bf16_kernel(
    const float* __restrict__ in, uint16_t* __restrict__ out, int n4) {
  int i = blockIdx.x * 256 + threadIdx.x;
  if (i >= n4) return;
  float4 v = ((const float4*)in)[i];
  ushort4 o;
  o.x = f2bf(v.x); o.y = f2bf(v.y); o.z = f2bf(v.z); o.w = f2bf(v.w);
  ((ushort4*)out)[i] = o;
}

// ---------------- kernel 2: fold everything into W5^T (N x K) bf16 ----------------
// Unchanged from the verified kernel (absmax 0.0156).
__global__ __launch_bounds__(256) void build_w_kernel(
    const float* __restrict__ weight,      // (4096, 1024)
    const float* __restrict__ mask,        // (4096, 1024)
    const float* __restrict__ in_scores,   // (512)
    const float* __restrict__ out_scores,  // (2048)
    const int*   __restrict__ in_mapping,  // (1024)
    const int*   __restrict__ out_mapping, // (4096)
    uint16_t*    __restrict__ w5t)         // (4096, 1024) bf16: row=o, col=i
{
  __shared__ float    w0[K_DIM], w1[K_DIM];
  __shared__ uint16_t o0[K_DIM], o1[K_DIM];

  const int mo = blockIdx.x;       // out-pair [0, 2048)
  const int t  = threadIdx.x;      // [0, 256)

  const int r0 = out_mapping[2 * mo];
  const int r1 = out_mapping[2 * mo + 1];

  ((float4*)w0)[t] = ((const float4*)(weight + (size_t)r0 * K_DIM))[t];
  ((float4*)w1)[t] = ((const float4*)(weight + (size_t)r1 * K_DIM))[t];

  const float ao = out_scores[mo];
  const float so = sinf(ao), co = cosf(ao);

  __syncthreads();

#pragma unroll
  for (int s = 0; s < 2; s++) {
    const int mi = t + s * 256;
    const float ai = in_scores[mi];
    const float si = sinf(ai), ci = cosf(ai);
    const int ia0 = in_mapping[2 * mi];
    const int ia1 = in_mapping[2 * mi + 1];

    const float w00 = w0[ia0], w01 = w0[ia1];
    const float w10 = w1[ia0], w11 = w1[ia1];

    float a00 =  ci * w00 + si * w01;
    float a01 = -si * w00 + ci * w01;
    float a10 =  ci * w10 + si * w11;
    float a11 = -si * w10 + ci * w11;

    float b00 = co * a00 - so * a10;
    float b10 = co * a01 - so * a11;
    float b01 = so * a00 + co * a10;
    float b11 = so * a01 + co * a11;

    const float2 mk0 = *(const float2*)&mask[(size_t)(2 * mo) * K_DIM + 2 * mi];
    const float2 mk1 = *(const float2*)&mask[(size_t)(2 * mo + 1) * K_DIM + 2 * mi];
    b00 *= mk0.x; b10 *= mk0.y;
    b01 *= mk1.x; b11 *= mk1.y;

    float c00 =  co * b00 + so * b01;
    float c10 =  co * b10 + so * b11;
    float c01 = -so * b00 + co * b01;
    float c11 = -so * b10 + co * b11;

    o0[ia0] = f2bf(ci * c00 - si * c10);
    o0[ia1] = f2bf(si * c00 + ci * c10);
    o1[ia0] = f2bf(ci * c01 - si * c11);
    o1[ia1] = f2bf(si * c01 + ci * c11);
  }

  __syncthreads();

  ((uint2*)(w5t + (size_t)r0 * K_DIM))[t] = ((const uint2*)o0)[t];
  ((uint2*)(w5t + (size_t)r1 * K_DIM))[t] = ((const uint2*)o1)[t];
}

// ---------------- kernel 3: GEMM out = A(8192x1024) * W5(1024x4096), bf16 MFMA ----------------
// R5: deep software pipeline (T3+T4+T5 from the catalog):
//   * tile 256x128, BK=64, 512 threads = 8 waves (4M x 2N), per-wave 64x64 out
//   * 3-slot circular LDS (A 3x32KB + B 3x16KB = 144 KB): stage(t+2) at tile t
//     targets slot (t+2)%3, whose readers finished at tile t-1's end barrier ->
//     race-free by construction.
//   * counted vmcnt: 6 global_load_lds per wave per tile; steady-state
//     vmcnt(12) (= stages t+1,t+2 in flight) proves tile t landed. NEVER
//     vmcnt(0) in the main loop; raw s_barrier (no __syncthreads drain).
//   * s_setprio(1) around the 32-MFMA cluster.
//   * same XOR source-pre-swizzle as R4 (conflicts measured 0): row-major
//     [rows][64] bf16, 16B chunk g stored at g ^ (row&7).
//   * XCD-bijective block swizzle (1024 blocks % 8 == 0).

__device__ __forceinline__ void async_load16(const uint16_t* g, uint16_t* lds_wave_uniform) {
  __builtin_amdgcn_global_load_lds(
      (const __attribute__((address_space(1))) uint32_t*)g,
      (__attribute__((address_space(3))) uint32_t*)lds_wave_uniform,
      16, 0, 0);
}

template <int VM>
__device__ __forceinline__ void wait_vm() {
  if constexpr (VM == 12)     asm volatile("s_waitcnt vmcnt(12)" ::: "memory");
  else if constexpr (VM == 6) asm volatile("s_waitcnt vmcnt(6)"  ::: "memory");
  else                        asm volatile("s_waitcnt vmcnt(0)"  ::: "memory");
}

__global__ __launch_bounds__(512, 2) void gemm_kernel(
    const uint16_t* __restrict__ A,   // (8192, 1024) bf16
    const uint16_t* __restrict__ BT,  // (4096, 1024) bf16 (W5^T, row=n, col=k)
    float* __restrict__ C)            // (8192, 4096) fp32
{
  __shared__ __align__(16) uint16_t As[3][256 * 64];  // 3 x 32 KB
  __shared__ __align__(16) uint16_t Bs[3][128 * 64];  // 3 x 16 KB

  const int tid  = threadIdx.x;     // 0..511
  const int w    = tid >> 6;        // wave 0..7
  const int lane = tid & 63;
  const int quad = lane >> 4;
  const int rr   = lane & 15;
  const int wm   = w >> 1;          // 0..3  (M quarter: 64 rows)
  const int wn   = w & 1;           // 0..1  (N half: 64 cols)

  // XCD-aware bijective swizzle: 1024 blocks, 8 XCDs, 128 per XCD chunk.
  const int flat = blockIdx.y * gridDim.x + blockIdx.x;   // 0..1023
  const int swz  = ((flat & 7) << 7) | (flat >> 3);
  const int bm   = swz >> 5;        // 0..31  (M tile of 256)
  const int bn   = swz & 31;        // 0..31  (N tile of 128)

  f32x4 acc[4][4] = {};

  // ---- staging source pointers (per-lane, XOR-preswizzled) ----
  // A: 2048 chunks of 16B per tile -> 4 insts/wave. chunk c = inst*512 + tid.
  // B: 1024 chunks -> 2 insts/wave.
  const uint16_t* gA[4];
  const uint16_t* gB[2];
#pragma unroll
  for (int ii = 0; ii < 4; ii++) {
    const int c   = ii * 512 + tid;
    const int row = c >> 3;                     // 0..255
    const int g   = (c & 7) ^ (row & 7);
    gA[ii] = A + (size_t)(bm * 256 + row) * K_DIM + g * 8;
  }
#pragma unroll
  for (int ii = 0; ii < 2; ii++) {
    const int c   = ii * 512 + tid;
    const int row = c >> 3;                     // 0..127
    const int g   = (c & 7) ^ (row & 7);
    gB[ii] = BT + (size_t)(bn * 128 + row) * K_DIM + g * 8;
  }

  // ---- fragment LDS offsets (per-lane, slot-invariant, uint16 units) ----
  int offA[4][2], offB[4][2];
#pragma unroll
  for (int i = 0; i < 4; i++) {
    const int r = wm * 64 + i * 16 + rr;
#pragma unroll
    for (int kh = 0; kh < 2; kh++) {
      const int gk = kh * 4 + quad;
      offA[i][kh] = (r * 8 + (gk ^ (r & 7))) * 8;
    }
  }
#pragma unroll
  for (int j = 0; j < 4; j++) {
    const int r = wn * 64 + j * 16 + rr;
#pragma unroll
    for (int kh = 0; kh < 2; kh++) {
      const int gk = kh * 4 + quad;
      offB[j][kh] = (r * 8 + (gk ^ (r & 7))) * 8;
    }
  }

#define STAGE(TIDX, SLOT)                                                     \
  do {                                                                        \
    const int k0s_ = (TIDX) * 64;                                             \
    _Pragma("unroll")                                                         \
    for (int ii_ = 0; ii_ < 4; ii_++)                                         \
      async_load16(gA[ii_] + k0s_, &As[SLOT][(ii_ * 512 + w * 64) * 8]);      \
    _Pragma("unroll")                                                         \
    for (int ii_ = 0; ii_ < 2; ii_++)                                         \
      async_load16(gB[ii_] + k0s_, &Bs[SLOT][(ii_ * 512 + w * 64) * 8]);      \
  } while (0)

#define TILE_BODY(VM, SLOT)                                                   \
  do {                                                                        \
    wait_vm<VM>();                        /* own stage of this tile landed */ \
    __builtin_amdgcn_s_barrier();         /* all waves' stages landed      */ \
    __builtin_amdgcn_sched_barrier(0);    /* no ds_read hoists above       */ \
    const uint16_t* as_ = &As[SLOT][0];                                       \
    const uint16_t* bs_ = &Bs[SLOT][0];                                       \
    bf16x8 af[4][2], bfv[4][2];                                               \
    _Pragma("unroll")                                                         \
    for (int i_ = 0; i_ < 4; i_++)                                            \
      _Pragma("unroll")                                                       \
      for (int kh_ = 0; kh_ < 2; kh_++)                                       \
        af[i_][kh_] = *reinterpret_cast<const bf16x8*>(as_ + offA[i_][kh_]);  \
    _Pragma("unroll")                                                         \
    for (int j_ = 0; j_ < 4; j_++)                                            \
      _Pragma("unroll")                                                       \
      for (int kh_ = 0; kh_ < 2; kh_++)                                       \
        bfv[j_][kh_] = *reinterpret_cast<const bf16x8*>(bs_ + offB[j_][kh_]); \
    __builtin_amdgcn_s_setprio(1);                                            \
    _Pragma("unroll")                                                         \
    for (int kh_ = 0; kh_ < 2; kh_++)                                         \
      _Pragma("unroll")                                                       \
      for (int i_ = 0; i_ < 4; i_++)                                          \
        _Pragma("unroll")                                                     \
        for (int j_ = 0; j_ < 4; j_++)                                        \
          acc[i_][j_] = __builtin_amdgcn_mfma_f32_16x16x32_bf16(              \
              af[i_][kh_], bfv[j_][kh_], acc[i_][j_], 0, 0, 0);               \
    __builtin_amdgcn_s_setprio(0);                                            \
    __builtin_amdgcn_s_barrier();         /* slot free for reuse           */ \
  } while (0)

  // ---- pipeline: 16 K-tiles, stage-ahead 2, 3-slot circular ----
  STAGE(0, 0);
  STAGE(1, 1);

  int sc = 0;  // slot of tile t
  int sn = 2;  // slot of tile t+2
  for (int t = 0; t < 14; ++t) {
    STAGE(t + 2, sn);
    TILE_BODY(12, sc);
    sc = (sc == 2) ? 0 : sc + 1;
    sn = (sn == 2) ? 0 : sn + 1;
  }
  TILE_BODY(6, sc);                 // t = 14 (slot 2): only stage(15) in flight
  sc = (sc == 2) ? 0 : sc + 1;
  TILE_BODY(0, sc);                 // t = 15 (slot 0): drain

#undef STAGE
#undef TILE_BODY

  // ---- epilogue: D layout col = lane&15 (n), row = quad*4 + reg (m) ----
#pragma unroll
  for (int i = 0; i < 4; i++) {
    const int row0 = bm * 256 + wm * 64 + i * 16 + quad * 4;
#pragma unroll
    for (int j = 0; j < 4; j++) {
      const int col = bn * 128 + wn * 64 + j * 16 + rr;
#pragma unroll
      for (int rg = 0; rg < 4; rg++) {
        C[(size_t)(row0 + rg) * N_DIM + col] = acc[i][j][rg];
      }
    }
  }
}

extern "C" void kernel_launch(void* const* d_in, const int* in_sizes, int n_in,
                              void* d_out, int out_size, void* d_ws, size_t ws_size,
                              hipStream_t stream) {
  const float* input      = (const float*)d_in[0];
  const float* weight     = (const float*)d_in[1];
  const float* mask       = (const float*)d_in[2];
  const float* in_scores  = (const float*)d_in[3];
  const float* out_scores = (const float*)d_in[4];
  const int*   in_mapping = (const int*)d_in[5];
  const int*   out_mapping= (const int*)d_in[6];
  // d_in[7] = out_mapping_reverse (folded away), d_in[8] = temperature (unused)
  float* out = (float*)d_out;

  uint16_t* a_bf16 = (uint16_t*)d_ws;                              // 8192*1024 bf16 = 16 MB
  uint16_t* w5t    = (uint16_t*)d_ws + (size_t)M_DIM * K_DIM;      // 4096*1024 bf16 = 8 MB

  convert_bf16_kernel<<<(M_DIM * K_DIM / 4 + 255) / 256, 256, 0, stream>>>(
      input, a_bf16, M_DIM * K_DIM / 4);

  build_w_kernel<<<2048, 256, 0, stream>>>(
      weight, mask, in_scores, out_scores, in_mapping, out_mapping, w5t);

  dim3 grid(32, 32);  // N/128 x M/256 = 1024 blocks, %8 == 0 for XCD swizzle
  gemm_kernel<<<grid, 512, 0, stream>>>(a_bf16, w5t, out);
}

// Round 2
// 260.862 us; speedup vs baseline: 1.0673x; 1.0673x over previous
//
#include <hip/hip_runtime.h>
#include <hip/hip_bf16.h>
#include <stdint.h>

// Problem dims (fixed): B=4, S=2048, IN=1024, OUT=4096 -> M=8192, K=1024, N=4096
#define M_DIM 8192
#define K_DIM 1024
#define N_DIM 4096

typedef __bf16 bf16x8 __attribute__((ext_vector_type(8)));
typedef float  f32x4  __attribute__((ext_vector_type(4)));

__device__ __forceinline__ uint16_t f2bf(float f) {
  union { float f; uint32_t u; } x; x.f = f;
  uint32_t u = x.u;
  return (uint16_t)((u + 0x7FFFu + ((u >> 16) & 1u)) >> 16);  // RNE
}

// ---------------- kernel 1: input fp32 -> bf16 ----------------
__global__ __launch_bounds__(256) void convert_bf16_kernel(
    const float* __restrict__ in, uint16_t* __restrict__ out, int n4) {
  int i = blockIdx.x * 256 + threadIdx.x;
  if (i >= n4) return;
  float4 v = ((const float4*)in)[i];
  ushort4 o;
  o.x = f2bf(v.x); o.y = f2bf(v.y); o.z = f2bf(v.z); o.w = f2bf(v.w);
  ((ushort4*)out)[i] = o;
}

// ---------------- kernel 2: fold everything into W5^T (N x K) bf16 ----------------
// Unchanged from the verified kernel (absmax 0.0156).
__global__ __launch_bounds__(256) void build_w_kernel(
    const float* __restrict__ weight,      // (4096, 1024)
    const float* __restrict__ mask,        // (4096, 1024)
    const float* __restrict__ in_scores,   // (512)
    const float* __restrict__ out_scores,  // (2048)
    const int*   __restrict__ in_mapping,  // (1024)
    const int*   __restrict__ out_mapping, // (4096)
    uint16_t*    __restrict__ w5t)         // (4096, 1024) bf16: row=o, col=i
{
  __shared__ float    w0[K_DIM], w1[K_DIM];
  __shared__ uint16_t o0[K_DIM], o1[K_DIM];

  const int mo = blockIdx.x;       // out-pair [0, 2048)
  const int t  = threadIdx.x;      // [0, 256)

  const int r0 = out_mapping[2 * mo];
  const int r1 = out_mapping[2 * mo + 1];

  ((float4*)w0)[t] = ((const float4*)(weight + (size_t)r0 * K_DIM))[t];
  ((float4*)w1)[t] = ((const float4*)(weight + (size_t)r1 * K_DIM))[t];

  const float ao = out_scores[mo];
  const float so = sinf(ao), co = cosf(ao);

  __syncthreads();

#pragma unroll
  for (int s = 0; s < 2; s++) {
    const int mi = t + s * 256;
    const float ai = in_scores[mi];
    const float si = sinf(ai), ci = cosf(ai);
    const int ia0 = in_mapping[2 * mi];
    const int ia1 = in_mapping[2 * mi + 1];

    const float w00 = w0[ia0], w01 = w0[ia1];
    const float w10 = w1[ia0], w11 = w1[ia1];

    float a00 =  ci * w00 + si * w01;
    float a01 = -si * w00 + ci * w01;
    float a10 =  ci * w10 + si * w11;
    float a11 = -si * w10 + ci * w11;

    float b00 = co * a00 - so * a10;
    float b10 = co * a01 - so * a11;
    float b01 = so * a00 + co * a10;
    float b11 = so * a01 + co * a11;

    const float2 mk0 = *(const float2*)&mask[(size_t)(2 * mo) * K_DIM + 2 * mi];
    const float2 mk1 = *(const float2*)&mask[(size_t)(2 * mo + 1) * K_DIM + 2 * mi];
    b00 *= mk0.x; b10 *= mk0.y;
    b01 *= mk1.x; b11 *= mk1.y;

    float c00 =  co * b00 + so * b01;
    float c10 =  co * b10 + so * b11;
    float c01 = -so * b00 + co * b01;
    float c11 = -so * b10 + co * b11;

    o0[ia0] = f2bf(ci * c00 - si * c10);
    o0[ia1] = f2bf(si * c00 + ci * c10);
    o1[ia0] = f2bf(ci * c01 - si * c11);
    o1[ia1] = f2bf(si * c01 + ci * c11);
  }

  __syncthreads();

  ((uint2*)(w5t + (size_t)r0 * K_DIM))[t] = ((const uint2*)o0)[t];
  ((uint2*)(w5t + (size_t)r1 * K_DIM))[t] = ((const uint2*)o1)[t];
}

// ---------------- kernel 3: GEMM out = A(8192x1024) * W5(1024x4096), bf16 MFMA ----------------
// R6: the m201-style 8-phase 256x256 schedule in plain HIP.
//   * BM=BN=256, BK=64, 512 threads = 8 waves (2M x 4N), per-wave 128x64 out.
//   * LDS 128 KB: As[2][2][128*64] + Bs[2][2][128*64] (2 dbuf x 2 halves).
//   * 4 phases per K-tile: {ds_read subtile || stage 1 half-tile} -> s_barrier
//     -> lgkmcnt(0) -> setprio(1) -> 16 MFMA -> setprio(0) -> s_barrier.
//   * Stage schedule from read lifetimes (B read only in phase 0, A group g in
//     phase g): p0/p1 stage A0/A1(t+1), p2/p3 stage B0/B1(t+2).
//   * ONE counted vmcnt(4) per K-tile at phase 3 (loads in flight 3-4 phases);
//     vmcnt(0) only in the epilogue (t==14). Raw s_barrier everywhere.
//   * XOR source-pre-swizzle identical to the verified R4 kernel (0 conflicts).

__device__ __forceinline__ void async_load16(const uint16_t* g, uint16_t* lds_wave_uniform) {
  __builtin_amdgcn_global_load_lds(
      (const __attribute__((address_space(1))) uint32_t*)g,
      (__attribute__((address_space(3))) uint32_t*)lds_wave_uniform,
      16, 0, 0);
}

__global__ __launch_bounds__(512, 2) void gemm_kernel(
    const uint16_t* __restrict__ A,   // (8192, 1024) bf16
    const uint16_t* __restrict__ BT,  // (4096, 1024) bf16 (W5^T, row=n, col=k)
    float* __restrict__ C)            // (8192, 4096) fp32
{
  __shared__ __align__(16) uint16_t As[2][2][128 * 64];  // 2buf x 2half x 16KB
  __shared__ __align__(16) uint16_t Bs[2][2][128 * 64];

  const int tid  = threadIdx.x;     // 0..511
  const int w    = tid >> 6;        // wave 0..7
  const int lane = tid & 63;
  const int quad = lane >> 4;
  const int rr   = lane & 15;
  const int wm   = w >> 2;          // 0..1  (M half of the tile: 128 rows)
  const int wn   = w & 3;           // 0..3  (N quarter: 64 cols)
  const int hA   = wm;              // A half this wave reads
  const int hB   = wn >> 1;         // B half this wave reads

  // XCD-bijective swizzle: 512 blocks, 64 per XCD, bn-fast within XCD.
  const int flat = blockIdx.y * gridDim.x + blockIdx.x;   // 0..511
  const int swz  = ((flat & 7) << 6) | (flat >> 3);
  const int bm   = swz >> 4;        // 0..31  (M tile of 256)
  const int bn   = swz & 15;        // 0..15  (N tile of 256)

  f32x4 acc[8][4] = {};

  // ---- staging source pointers (per-lane, XOR-preswizzled) ----
  // One half-tile = 128 rows x 64 k = 1024 chunks of 16B; thread handles
  // chunks {tid, tid+512}. chunk c: row=c>>3, stored k-group h=c&7 holds
  // global k-group g = h ^ (row&7).
  const uint16_t* gA[2];
  const uint16_t* gB[2];
#pragma unroll
  for (int ii = 0; ii < 2; ii++) {
    const int c   = ii * 512 + tid;
    const int row = c >> 3;                     // 0..127
    const int g   = (c & 7) ^ (row & 7);
    gA[ii] = A  + (size_t)(bm * 256 + row) * K_DIM + g * 8;
    gB[ii] = BT + (size_t)(bn * 256 + row) * K_DIM + g * 8;
  }

#define STAGE_A(BUF, H, KT)                                                   \
  do {                                                                        \
    _Pragma("unroll")                                                         \
    for (int ii_ = 0; ii_ < 2; ii_++)                                         \
      async_load16(gA[ii_] + (H) * (128 * K_DIM) + (KT) * 64,                 \
                   &As[BUF][H][(ii_ * 512 + w * 64) * 8]);                    \
  } while (0)

#define STAGE_B(BUF, H, KT)                                                   \
  do {                                                                        \
    _Pragma("unroll")                                                         \
    for (int ii_ = 0; ii_ < 2; ii_++)                                         \
      async_load16(gB[ii_] + (H) * (128 * K_DIM) + (KT) * 64,                 \
                   &Bs[BUF][H][(ii_ * 512 + w * 64) * 8]);                    \
  } while (0)

  // ---- fragment LDS offsets (within the wave's half buffer, u16 units) ----
  int offA[8][2], offB[4][2];
#pragma unroll
  for (int i = 0; i < 8; i++) {
    const int r = i * 16 + rr;                  // row within A half
#pragma unroll
    for (int s = 0; s < 2; s++) {
      const int gk = s * 4 + quad;
      offA[i][s] = (r * 8 + (gk ^ (r & 7))) * 8;
    }
  }
#pragma unroll
  for (int j = 0; j < 4; j++) {
    const int r = (wn & 1) * 64 + j * 16 + rr;  // row within B half
#pragma unroll
    for (int s = 0; s < 2; s++) {
      const int gk = s * 4 + quad;
      offB[j][s] = (r * 8 + (gk ^ (r & 7))) * 8;
    }
  }

  // One phase: 4 A-frag ds_reads (+8 B-frag reads in phase 0, issued by caller),
  // one half-tile stage, optional counted vmcnt, barrier, lgkm drain, 16 MFMA.
#define PHASE(P, STAGE_STMT, WAIT_STMT)                                        \
  {                                                                            \
    bf16x8 af[2][2];                                                           \
    _Pragma("unroll")                                                          \
    for (int d_ = 0; d_ < 2; d_++)                                             \
      _Pragma("unroll")                                                        \
      for (int s_ = 0; s_ < 2; s_++)                                           \
        af[d_][s_] = *reinterpret_cast<const bf16x8*>(asb + offA[2*(P)+d_][s_]); \
    STAGE_STMT;                                                                \
    WAIT_STMT;                                                                 \
    __builtin_amdgcn_sched_barrier(0);                                         \
    __builtin_amdgcn_s_barrier();                                              \
    asm volatile("s_waitcnt lgkmcnt(0)" ::: "memory");                         \
    __builtin_amdgcn_sched_barrier(0);                                         \
    __builtin_amdgcn_s_setprio(1);                                             \
    _Pragma("unroll")                                                          \
    for (int s_ = 0; s_ < 2; s_++)                                             \
      _Pragma("unroll")                                                        \
      for (int d_ = 0; d_ < 2; d_++)                                           \
        _Pragma("unroll")                                                      \
        for (int j_ = 0; j_ < 4; j_++)                                         \
          acc[2*(P)+d_][j_] = __builtin_amdgcn_mfma_f32_16x16x32_bf16(         \
              af[d_][s_], bfv[j_][s_], acc[2*(P)+d_][j_], 0, 0, 0);            \
    __builtin_amdgcn_s_setprio(0);                                             \
    __builtin_amdgcn_sched_barrier(0);                                         \
    __builtin_amdgcn_s_barrier();                                              \
    __builtin_amdgcn_sched_barrier(0);                                         \
  }

  // ---- prologue: B(0), A(0), B(1); keep last 2 stages (4 loads) in flight ----
  STAGE_B(0, 0, 0); STAGE_B(0, 1, 0);
  STAGE_A(0, 0, 0); STAGE_A(0, 1, 0);
  STAGE_B(1, 0, 1); STAGE_B(1, 1, 1);
  asm volatile("s_waitcnt vmcnt(4)" ::: "memory");   // B(0), A(0) landed
  __builtin_amdgcn_s_barrier();
  __builtin_amdgcn_sched_barrier(0);

  // ---- main loop: 16 K-tiles x 4 phases ----
  for (int t = 0; t < 16; ++t) {
    const int buf  = t & 1;
    const int nbuf = buf ^ 1;
    const uint16_t* asb = &As[buf][hA][0];
    const uint16_t* bsb = &Bs[buf][hB][0];

    // B fragments for the whole tile (read only here; slots dead afterwards)
    bf16x8 bfv[4][2];
#pragma unroll
    for (int j = 0; j < 4; j++)
#pragma unroll
      for (int s = 0; s < 2; s++)
        bfv[j][s] = *reinterpret_cast<const bf16x8*>(bsb + offB[j][s]);

    PHASE(0, { if (t < 15) STAGE_A(nbuf, 0, t + 1); }, {});
    PHASE(1, { if (t < 15) STAGE_A(nbuf, 1, t + 1); }, {});
    PHASE(2, { if (t < 14) STAGE_B(buf, 0, t + 2); }, {});
    PHASE(3, { if (t < 14) STAGE_B(buf, 1, t + 2); },
          { if (t < 14)       { asm volatile("s_waitcnt vmcnt(4)" ::: "memory"); }
            else if (t == 14) { asm volatile("s_waitcnt vmcnt(0)" ::: "memory"); } });
  }

#undef PHASE
#undef STAGE_A
#undef STAGE_B

  // ---- epilogue: D layout col = lane&15 (n), row = quad*4 + reg (m) ----
#pragma unroll
  for (int i = 0; i < 8; i++) {
    const int row0 = bm * 256 + wm * 128 + i * 16 + quad * 4;
#pragma unroll
    for (int j = 0; j < 4; j++) {
      const int col = bn * 256 + wn * 64 + j * 16 + rr;
#pragma unroll
      for (int rg = 0; rg < 4; rg++) {
        C[(size_t)(row0 + rg) * N_DIM + col] = acc[i][j][rg];
      }
    }
  }
}

extern "C" void kernel_launch(void* const* d_in, const int* in_sizes, int n_in,
                              void* d_out, int out_size, void* d_ws, size_t ws_size,
                              hipStream_t stream) {
  const float* input      = (const float*)d_in[0];
  const float* weight     = (const float*)d_in[1];
  const float* mask       = (const float*)d_in[2];
  const float* in_scores  = (const float*)d_in[3];
  const float* out_scores = (const float*)d_in[4];
  const int*   in_mapping = (const int*)d_in[5];
  const int*   out_mapping= (const int*)d_in[6];
  // d_in[7] = out_mapping_reverse (folded away), d_in[8] = temperature (unused)
  float* out = (float*)d_out;

  uint16_t* a_bf16 = (uint16_t*)d_ws;                              // 8192*1024 bf16 = 16 MB
  uint16_t* w5t    = (uint16_t*)d_ws + (size_t)M_DIM * K_DIM;      // 4096*1024 bf16 = 8 MB

  convert_bf16_kernel<<<(M_DIM * K_DIM / 4 + 255) / 256, 256, 0, stream>>>(
      input, a_bf16, M_DIM * K_DIM / 4);

  build_w_kernel<<<2048, 256, 0, stream>>>(
      weight, mask, in_scores, out_scores, in_mapping, out_mapping, w5t);

  dim3 grid(N_DIM / 256, M_DIM / 256);  // (16, 32) = 512 blocks, %8 == 0
  gemm_kernel<<<grid, 512, 0, stream>>>(a_bf16, w5t, out);
}